// Round 14
// baseline (1096.985 us; speedup 1.0000x reference)
//
#include <hip/hip_runtime.h>
#include <hip/hip_bf16.h>

typedef unsigned short ushort_t;
typedef unsigned int uint_t;
typedef __attribute__((ext_vector_type(8))) short short8;
typedef __attribute__((ext_vector_type(4))) float f32x4;

#define DIMC 256
#define D_INNER 512
#define D_STATE 64
#define DT_RANK 16
#define LSEQ 4096
#define BS2 8            // 2*BS batches through mamba
#define MROWS (BS2*LSEQ) // 32768

__device__ __forceinline__ float b2f(ushort_t u) {
    union { uint_t i; float f; } v; v.i = ((uint_t)u) << 16; return v.f;
}
__device__ __forceinline__ ushort_t f2b(float f) {
    union { float f; uint_t i; } v; v.f = f;
    uint_t r = v.i + 0x7FFFu + ((v.i >> 16) & 1u);   // RNE
    return (ushort_t)(r >> 16);
}

// async global->LDS 16B per lane (HW: wave-uniform LDS base + lane*16)
typedef __attribute__((address_space(1))) const unsigned int gas_u32;
typedef __attribute__((address_space(3))) unsigned int las_u32;
__device__ __forceinline__ void gload16(const void* g, void* l) {
    __builtin_amdgcn_global_load_lds((gas_u32*)g, (las_u32*)l, 16, 0, 0);
}

// ---------------- fp32 -> bf16 conversion of the 3 MFMA weight mats ----------------
__global__ void cvtw3(const float* __restrict__ s0, ushort_t* __restrict__ d0,
                      const float* __restrict__ s1, ushort_t* __restrict__ d1,
                      const float* __restrict__ s2, ushort_t* __restrict__ d2) {
    int i = blockIdx.x * 256 + threadIdx.x;
    const int n0 = 1024 * 256, n1 = 144 * 512, n2 = 256 * 512;
    if (i < n0) d0[i] = f2b(s0[i]);
    else if (i < n0 + n1) d1[i - n0] = f2b(s1[i - n0]);
    else if (i < n0 + n1 + n2) d2[i - n0 - n1] = f2b(s2[i - n0 - n1]);
}

// ---------------- LN1 + build xm (both orders), fp32 in, bf16 out ----------------
__global__ void ln1_build_xm(const float* __restrict__ x,
                             const float* __restrict__ w,
                             const float* __restrict__ bb,
                             ushort_t* __restrict__ xm) {
    int row = blockIdx.x;            // b*4096 + l  (b in 0..3)
    int c = threadIdx.x;             // 0..255
    float v = x[(size_t)row * DIMC + c];
    float s1 = v, s2 = v * v;
    for (int off = 32; off; off >>= 1) {
        s1 += __shfl_xor(s1, off, 64);
        s2 += __shfl_xor(s2, off, 64);
    }
    __shared__ float sa[4], sb[4];
    int widx = c >> 6, lane = c & 63;
    if (lane == 0) { sa[widx] = s1; sb[widx] = s2; }
    __syncthreads();
    s1 = sa[0] + sa[1] + sa[2] + sa[3];
    s2 = sb[0] + sb[1] + sb[2] + sb[3];
    float mu = s1 * (1.0f / 256.0f);
    float var = s2 * (1.0f / 256.0f) - mu * mu;
    float xn = (v - mu) * rsqrtf(var + 1e-6f) * w[c] + bb[c];
    ushort_t o = f2b(xn);
    int b = row >> 12, l = row & 4095, i = l >> 6, j = l & 63;
    xm[((size_t)b * LSEQ + l) * DIMC + c] = o;
    xm[((size_t)(4 + b) * LSEQ + (j * 64 + i)) * DIMC + c] = o;
}

// ---------------- 128x128 LDS-tiled NT GEMM with global_load_lds staging ----------------
__global__ void __launch_bounds__(256, 4)
gemm128(const ushort_t* __restrict__ A,
        const ushort_t* __restrict__ W,
        ushort_t* __restrict__ C, int M, int N, int K) {
    __shared__ ushort_t Ash[128 * 32];
    __shared__ ushort_t Bsh[128 * 32];
    int tid = threadIdx.x;
    int lane = tid & 63, widx = tid >> 6;
    int wm = widx & 1, wn = widx >> 1;
    int l16 = lane & 15, quad = lane >> 4;
    int mblk = blockIdx.x * 128, nblk = blockIdx.y * 128;
    f32x4 acc[4][4];
    #pragma unroll
    for (int i = 0; i < 4; ++i)
        #pragma unroll
        for (int j = 0; j < 4; ++j)
            acc[i][j] = f32x4{0.0f, 0.0f, 0.0f, 0.0f};
    int srow = tid >> 2;
    int sseg = (tid & 3) * 8;
    bool jv[4];
    #pragma unroll
    for (int j = 0; j < 4; ++j) jv[j] = (nblk + wn * 64 + j * 16) < N;

    for (int k0 = 0; k0 < K; k0 += 32) {
        __syncthreads();
        #pragma unroll
        for (int q = 0; q < 2; ++q) {
            int row = q * 64 + srow;
            gload16(&A[(size_t)(mblk + row) * K + k0 + sseg], &Ash[row * 32 + sseg]);
            gload16(&W[(size_t)(nblk + row) * K + k0 + sseg], &Bsh[row * 32 + sseg]);
        }
        __syncthreads();
        short8 af[4], bf[4];
        #pragma unroll
        for (int i = 0; i < 4; ++i)
            af[i] = *(const short8*)&Ash[(wm * 64 + i * 16 + l16) * 32 + quad * 8];
        #pragma unroll
        for (int j = 0; j < 4; ++j)
            bf[j] = *(const short8*)&Bsh[(wn * 64 + j * 16 + l16) * 32 + quad * 8];
        #pragma unroll
        for (int i = 0; i < 4; ++i)
            #pragma unroll
            for (int j = 0; j < 4; ++j)
                if (jv[j])
                    acc[i][j] = __builtin_amdgcn_mfma_f32_16x16x32_bf16(af[i], bf[j], acc[i][j], 0, 0, 0);
    }
    #pragma unroll
    for (int i = 0; i < 4; ++i) {
        #pragma unroll
        for (int j = 0; j < 4; ++j) {
            if (!jv[j]) continue;
            int col = nblk + wn * 64 + j * 16 + l16;
            #pragma unroll
            for (int r = 0; r < 4; ++r) {
                int row = mblk + wm * 64 + i * 16 + quad * 4 + r;
                C[(size_t)row * N + col] = f2b(acc[i][j][r]);
            }
        }
    }
}

// ---------------- gemm128 variant: K=256, N=1024, split outputs at col 512 ----------------
__global__ void __launch_bounds__(256, 4)
gemm128_split(const ushort_t* __restrict__ A,
              const ushort_t* __restrict__ W,
              ushort_t* __restrict__ outX,   // cols 0..511
              ushort_t* __restrict__ outZ) { // cols 512..1023
    const int K = 256;
    __shared__ ushort_t Ash[128 * 32];
    __shared__ ushort_t Bsh[128 * 32];
    int tid = threadIdx.x;
    int lane = tid & 63, widx = tid >> 6;
    int wm = widx & 1, wn = widx >> 1;
    int l16 = lane & 15, quad = lane >> 4;
    int mblk = blockIdx.x * 128, nblk = blockIdx.y * 128;
    f32x4 acc[4][4];
    #pragma unroll
    for (int i = 0; i < 4; ++i)
        #pragma unroll
        for (int j = 0; j < 4; ++j)
            acc[i][j] = f32x4{0.0f, 0.0f, 0.0f, 0.0f};
    int srow = tid >> 2;
    int sseg = (tid & 3) * 8;
    for (int k0 = 0; k0 < K; k0 += 32) {
        __syncthreads();
        #pragma unroll
        for (int q = 0; q < 2; ++q) {
            int row = q * 64 + srow;
            gload16(&A[(size_t)(mblk + row) * K + k0 + sseg], &Ash[row * 32 + sseg]);
            gload16(&W[(size_t)(nblk + row) * K + k0 + sseg], &Bsh[row * 32 + sseg]);
        }
        __syncthreads();
        short8 af[4], bf[4];
        #pragma unroll
        for (int i = 0; i < 4; ++i)
            af[i] = *(const short8*)&Ash[(wm * 64 + i * 16 + l16) * 32 + quad * 8];
        #pragma unroll
        for (int j = 0; j < 4; ++j)
            bf[j] = *(const short8*)&Bsh[(wn * 64 + j * 16 + l16) * 32 + quad * 8];
        #pragma unroll
        for (int i = 0; i < 4; ++i)
            #pragma unroll
            for (int j = 0; j < 4; ++j)
                acc[i][j] = __builtin_amdgcn_mfma_f32_16x16x32_bf16(af[i], bf[j], acc[i][j], 0, 0, 0);
    }
    #pragma unroll
    for (int i = 0; i < 4; ++i) {
        #pragma unroll
        for (int j = 0; j < 4; ++j) {
            int colg = nblk + wn * 64 + j * 16 + l16;    // tile never straddles 512
            ushort_t* dst = (colg < 512) ? outX : outZ;
            int col = colg & 511;
            #pragma unroll
            for (int r = 0; r < 4; ++r) {
                int row = mblk + wm * 64 + i * 16 + quad * 4 + r;
                dst[(size_t)row * 512 + col] = f2b(acc[i][j][r]);
            }
        }
    }
}

// ---------------- tiled conv(4)+SiLU: all-coalesced, dual output ----------------
__global__ void conv_silu_t(const ushort_t* __restrict__ xh,
                            const float* __restrict__ cw,
                            const float* __restrict__ cb,
                            ushort_t* __restrict__ xc,
                            ushort_t* __restrict__ u_T) {
    int bt0 = blockIdx.x * 64;
    int d0  = blockIdx.y * 64;
    int b   = bt0 >> 12;
    int t0  = bt0 & 4095;
    __shared__ ushort_t tin[67][66];
    __shared__ ushort_t tout[64][66];
    int tid = threadIdx.x, lane = tid & 63, widx = tid >> 6;
    for (int r = widx; r < 67; r += 4) {
        int tt = t0 - 3 + r;
        tin[r][lane] = (tt >= 0) ? xh[((size_t)bt0 - 3 + r) * 512 + d0 + lane] : (ushort_t)0;
    }
    __syncthreads();
    for (int dd = widx; dd < 64; dd += 4) {
        int d = d0 + dd;
        float acc = cb[d];
        #pragma unroll
        for (int k = 0; k < 4; ++k)
            acc += cw[d * 4 + k] * b2f(tin[lane + k][dd]);
        float s = acc / (1.0f + __expf(-acc));
        ushort_t o = f2b(s);
        u_T[((size_t)b * 512 + d) * 4096 + t0 + lane] = o;
        tout[lane][dd] = o;
    }
    __syncthreads();
    for (int r = widx; r < 64; r += 4)
        xc[((size_t)bt0 + r) * 512 + d0 + lane] = tout[r][lane];
}

// ---------------- tiled dt/w: dt_T = softplus(...), w_T = dt*u  ----------------
__global__ void dt_sp_t(const ushort_t* __restrict__ xdbl,
                        const float* __restrict__ wdt,
                        const float* __restrict__ bdt,
                        const ushort_t* __restrict__ u_T,
                        ushort_t* __restrict__ dt_T,
                        ushort_t* __restrict__ w_T) {
    int bt0 = blockIdx.x * 64;
    int d0  = blockIdx.y * 64;
    int b   = bt0 >> 12;
    int t0  = bt0 & 4095;
    __shared__ float din[64][17];
    int tid = threadIdx.x;
    for (int i = tid; i < 64 * 16; i += 256) {
        int r = i >> 4, k = i & 15;
        din[r][k] = b2f(xdbl[((size_t)bt0 + r) * 144 + k]);
    }
    __syncthreads();
    int lane = tid & 63, widx = tid >> 6;
    for (int dd = widx; dd < 64; dd += 4) {
        int d = d0 + dd;
        float acc = bdt[d];
        #pragma unroll
        for (int k = 0; k < 16; ++k)
            acc += din[lane][k] * wdt[d * 16 + k];
        float sp = (acc > 20.0f) ? acc : log1pf(__expf(acc));
        size_t idx = ((size_t)b * 512 + d) * 4096 + t0 + lane;
        dt_T[idx] = f2b(sp);
        float uvv = b2f(u_T[idx]);
        w_T[idx] = f2b(sp * uvv);
    }
}

// ---------------- selective scan v9: SGPR-batched dt/w prefetch ----------------
template<int LVL>
__device__ __forceinline__ float merge_lvl_t(float left, float right, int lane) {
    bool bit = (lane >> LVL) & 1;
    float send = bit ? left : right;
    float keep = bit ? right : left;
    float recv;
    if constexpr (LVL == 0)
        recv = __int_as_float(__builtin_amdgcn_update_dpp(
            0, __float_as_int(send), 0xB1, 0xF, 0xF, false));   // quad_perm xor1
    else if constexpr (LVL == 1)
        recv = __int_as_float(__builtin_amdgcn_update_dpp(
            0, __float_as_int(send), 0x4E, 0xF, 0xF, false));   // quad_perm xor2
    else
        recv = __shfl_xor(send, 1 << LVL, 64);
    return keep + recv;
}

__global__ void __launch_bounds__(256, 4)
scan9(const ushort_t* __restrict__ dt_T,
      ushort_t* uT_ysT,
      const ushort_t* __restrict__ w_T,
      const ushort_t* __restrict__ xdbl,
      const float* __restrict__ Alog,
      const float* __restrict__ Dp) {
    __shared__ float2 BCsh[64][64];   // [t][s] = (B,C) fp32 pair -> ds_read_b64
    int tid = threadIdx.x;
    int lane = tid & 63, widx = tid >> 6;
    int wid = blockIdx.x * 4 + widx;
    int b = wid >> 9, d = wid & 511;
    float a2 = -__expf(Alog[d * 64 + lane]) * 1.442695041f;   // log2(e) folded
    float Dd = Dp[d];
    float h = 0.0f;
    size_t rowT = ((size_t)b * 512 + d) * 4096;
    uint_t rowTu = __builtin_amdgcn_readfirstlane((uint_t)rowT);
    size_t base = (size_t)b * LSEQ;
    for (int t0 = 0; t0 < LSEQ; t0 += 64) {
        __syncthreads();
        // batched uniform prefetch of this chunk's dt/w into SGPRs
        const uint_t* dtw = (const uint_t*)(dt_T + rowTu) + (t0 >> 1);
        const uint_t* wwp = (const uint_t*)(w_T + rowTu) + (t0 >> 1);
        uint_t pds[32], pws[32];
        #pragma unroll
        for (int k2 = 0; k2 < 32; ++k2) {
            pds[k2] = dtw[k2];
            pws[k2] = wwp[k2];
        }
        // stage B,C (64t x 64s) as fp32 pairs
        for (int i = tid; i < 2048; i += 256) {
            int t = i >> 5, kk = (i & 31) * 2;
            const ushort_t* rp = xdbl + (base + t0 + t) * 144 + 16;
            uint_t wB = *(const uint_t*)(rp + kk);
            uint_t wC = *(const uint_t*)(rp + 64 + kk);
            BCsh[t][kk]     = make_float2(__uint_as_float(wB << 16),
                                          __uint_as_float(wC << 16));
            BCsh[t][kk + 1] = make_float2(__uint_as_float(wB & 0xFFFF0000u),
                                          __uint_as_float(wC & 0xFFFF0000u));
        }
        float uv = b2f(uT_ysT[rowT + t0 + lane]);
        __syncthreads();
        float acc[4], s4, s5, yfin = 0.0f, v16 = 0.0f;
        #pragma unroll 1
        for (int j1 = 0; j1 < 4; ++j1) {
            #pragma unroll
            for (int jj = 0; jj < 16; ++jj) {
                int j = j1 * 16 + jj;
                uint_t pd = pds[j >> 1];
                uint_t pw = pws[j >> 1];
                float sdt = __uint_as_float((jj & 1) ? (pd & 0xFFFF0000u) : (pd << 16));
                float sw  = __uint_as_float((jj & 1) ? (pw & 0xFFFF0000u) : (pw << 16));
                float2 bc = BCsh[j][lane];          // single ds_read_b64
                float dA = __builtin_amdgcn_exp2f(sdt * a2);  // raw v_exp_f32
                float Bw = sw * bc.x;
                h = dA * h + Bw;
                float v = h * bc.y;
                const int dest = (jj == 15) ? 4 : __builtin_ctz(~(unsigned)jj);
                if (0 < dest) v = merge_lvl_t<0>(acc[0], v, lane);
                if (1 < dest) v = merge_lvl_t<1>(acc[1], v, lane);
                if (2 < dest) v = merge_lvl_t<2>(acc[2], v, lane);
                if (3 < dest) v = merge_lvl_t<3>(acc[3], v, lane);
                if (jj == 15) v16 = v;
                else acc[dest] = v;
            }
            if ((j1 & 1) == 0) {
                s4 = v16;
            } else {
                float m = merge_lvl_t<4>(s4, v16, lane);
                if (j1 == 1) s5 = m;
                else yfin = merge_lvl_t<5>(s5, m, lane);
            }
        }
        float y = yfin + uv * Dd;
        uT_ysT[rowT + t0 + lane] = f2b(y);
    }
}

// ---------------- gate + transpose: ys[bt,d] = ysT[b,d,t] * silu(z[bt,d]) ----------------
__global__ void gate_t(const ushort_t* __restrict__ ysT,
                       const ushort_t* __restrict__ zb,
                       ushort_t* __restrict__ ys) {
    int bt0 = blockIdx.x * 64;
    int d0  = blockIdx.y * 64;
    int b   = bt0 >> 12;
    int t0  = bt0 & 4095;
    __shared__ ushort_t tile[64][66];
    int tid = threadIdx.x, lane = tid & 63, widx = tid >> 6;
    for (int dd = widx; dd < 64; dd += 4)
        tile[dd][lane] = ysT[((size_t)b * 512 + d0 + dd) * 4096 + t0 + lane];
    __syncthreads();
    for (int r = widx; r < 64; r += 4) {
        float zv = b2f(zb[((size_t)bt0 + r) * 512 + d0 + lane]);
        float yv = b2f(tile[lane][r]);
        float g = zv / (1.0f + __expf(-zv));
        ys[((size_t)bt0 + r) * 512 + d0 + lane] = f2b(yv * g);
    }
}

// ---------------- final LN + transpose-combine + residual (fp32 out) ----------------
__global__ void final_ln_add(const ushort_t* __restrict__ outm,
                             const float* __restrict__ x,
                             const float* __restrict__ w,
                             const float* __restrict__ bb,
                             float* __restrict__ out) {
    int row = blockIdx.x;
    int c = threadIdx.x;
    int b = row >> 12, l = row & 4095, i = l >> 6, j = l & 63;
    size_t rA = ((size_t)b * LSEQ + l) * DIMC;
    size_t rB = ((size_t)(4 + b) * LSEQ + (j * 64 + i)) * DIMC;
    float va = b2f(outm[rA + c]);
    float vb = b2f(outm[rB + c]);
    float s1 = va, s2 = va * va, s3 = vb, s4 = vb * vb;
    for (int off = 32; off; off >>= 1) {
        s1 += __shfl_xor(s1, off, 64);
        s2 += __shfl_xor(s2, off, 64);
        s3 += __shfl_xor(s3, off, 64);
        s4 += __shfl_xor(s4, off, 64);
    }
    __shared__ float sm[4][4];
    int widx = c >> 6, lane = c & 63;
    if (lane == 0) { sm[widx][0] = s1; sm[widx][1] = s2; sm[widx][2] = s3; sm[widx][3] = s4; }
    __syncthreads();
    s1 = sm[0][0] + sm[1][0] + sm[2][0] + sm[3][0];
    s2 = sm[0][1] + sm[1][1] + sm[2][1] + sm[3][1];
    s3 = sm[0][2] + sm[1][2] + sm[2][2] + sm[3][2];
    s4 = sm[0][3] + sm[1][3] + sm[2][3] + sm[3][3];
    float muA = s1 * (1.0f / 256.0f), varA = s2 * (1.0f / 256.0f) - muA * muA;
    float muB = s3 * (1.0f / 256.0f), varB = s4 * (1.0f / 256.0f) - muB * muB;
    float lw = w[c], lb = bb[c];
    float ya = (va - muA) * rsqrtf(varA + 1e-6f) * lw + lb;
    float yb = (vb - muB) * rsqrtf(varB + 1e-6f) * lw + lb;
    float xo = x[(size_t)row * DIMC + c];
    out[(size_t)row * DIMC + c] = xo + ya + yb;
}

extern "C" void kernel_launch(void* const* d_in, const int* in_sizes, int n_in,
                              void* d_out, int out_size, void* d_ws, size_t ws_size,
                              hipStream_t stream) {
    const float* x      = (const float*)d_in[0];
    const float* ln1_w  = (const float*)d_in[1];
    const float* ln1_b  = (const float*)d_in[2];
    const float* ln2_w  = (const float*)d_in[3];
    const float* ln2_b  = (const float*)d_in[4];
    const float* W_in   = (const float*)d_in[5];
    const float* conv_w = (const float*)d_in[6];
    const float* conv_b = (const float*)d_in[7];
    const float* W_x    = (const float*)d_in[8];
    const float* W_dt   = (const float*)d_in[9];
    const float* b_dt   = (const float*)d_in[10];
    const float* A_log  = (const float*)d_in[11];
    const float* D_par  = (const float*)d_in[12];
    const float* W_out  = (const float*)d_in[13];
    float* out = (float*)d_out;

    // ---- workspace (~152 MB) ----
    char* ws = (char*)d_ws;
    size_t off = 0;
    ushort_t* wb_in  = (ushort_t*)(ws + off); off += (size_t)1024 * 256 * 2;
    ushort_t* wb_x   = (ushort_t*)(ws + off); off += (size_t)144 * 512 * 2;
    ushort_t* wb_out = (ushort_t*)(ws + off); off += (size_t)256 * 512 * 2;
    const size_t R0 = (size_t)MROWS * DIMC * 2;
    const size_t R1 = (size_t)MROWS * 512 * 2;
    ushort_t* r0 = (ushort_t*)(ws + off); off += R0;   // xm -> xdbl -> outm
    ushort_t* r1 = (ushort_t*)(ws + off); off += R1;   // xhalf -> dt_T
    ushort_t* r2 = (ushort_t*)(ws + off); off += R1;   // z
    ushort_t* r3 = (ushort_t*)(ws + off); off += R1;   // xc -> w_T -> ys
    ushort_t* r4 = (ushort_t*)(ws + off); off += R1;   // u_T -> ysT (in place)

    ushort_t* xm    = r0;
    ushort_t* xdbl  = r0;
    ushort_t* outm  = r0;
    ushort_t* xhalf = r1;
    ushort_t* dt_T  = r1;
    ushort_t* zb    = r2;
    ushort_t* xc    = r3;
    ushort_t* w_T   = r3;
    ushort_t* ys    = r3;
    ushort_t* u_T   = r4;

    // 0. convert MFMA weights fp32 -> bf16 (one launch)
    const int ncvt = 1024 * 256 + 144 * 512 + 256 * 512;
    hipLaunchKernelGGL(cvtw3, dim3((ncvt + 255) / 256), dim3(256), 0, stream,
                       W_in, wb_in, W_x, wb_x, W_out, wb_out);

    // A. LayerNorm + dual-order xm
    hipLaunchKernelGGL(ln1_build_xm, dim3(4 * LSEQ), dim3(256), 0, stream,
                       x, ln1_w, ln1_b, xm);
    // B. one launch: cols<512 -> xhalf, cols>=512 -> zb
    hipLaunchKernelGGL(gemm128_split, dim3(MROWS / 128, 8), dim3(256), 0, stream,
                       xm, wb_in, xhalf, zb);
    // C. tiled conv + SiLU: xhalf -> xc[bt,d] + u_T[b,d,t]
    hipLaunchKernelGGL(conv_silu_t, dim3(MROWS / 64, 8), dim3(256), 0, stream,
                       xhalf, conv_w, conv_b, xc, u_T);
    // D. x_dbl = xc @ W_x^T   (N=144, K=512)
    hipLaunchKernelGGL(gemm128, dim3(MROWS / 128, 2), dim3(256), 0, stream,
                       xc, wb_x, xdbl, MROWS, 144, 512);
    // E. dt_T = softplus(...), w_T = dt*u  [b,d,t]
    hipLaunchKernelGGL(dt_sp_t, dim3(MROWS / 64, 8), dim3(256), 0, stream,
                       xdbl, W_dt, b_dt, u_T, dt_T, w_T);
    // F. selective scan v9: u_T -> ysT in place
    hipLaunchKernelGGL(scan9, dim3(BS2 * 512 / 4), dim3(256), 0, stream,
                       dt_T, u_T, w_T, xdbl, A_log, D_par);
    // G. gate + transpose: ys[bt,d] = ysT * silu(z)
    hipLaunchKernelGGL(gate_t, dim3(MROWS / 64, 8), dim3(256), 0, stream,
                       u_T, zb, ys);
    // H. outm = ys @ W_out^T   (N=256, K=512)
    hipLaunchKernelGGL(gemm128, dim3(MROWS / 128, 2), dim3(256), 0, stream,
                       ys, wb_out, outm, MROWS, 256, 512);
    // I. final LN + transpose combine + residual (fp32 out)
    hipLaunchKernelGGL(final_ln_add, dim3(4 * LSEQ), dim3(256), 0, stream,
                       outm, x, ln2_w, ln2_b, out);
}

// Round 15
// 738.678 us; speedup vs baseline: 1.4851x; 1.4851x over previous
//
#include <hip/hip_runtime.h>
#include <hip/hip_bf16.h>

typedef unsigned short ushort_t;
typedef unsigned int uint_t;
typedef __attribute__((ext_vector_type(8))) short short8;
typedef __attribute__((ext_vector_type(4))) float f32x4;

#define DIMC 256
#define D_INNER 512
#define D_STATE 64
#define DT_RANK 16
#define LSEQ 4096
#define BS2 8            // 2*BS batches through mamba
#define MROWS (BS2*LSEQ) // 32768

__device__ __forceinline__ float b2f(ushort_t u) {
    union { uint_t i; float f; } v; v.i = ((uint_t)u) << 16; return v.f;
}
__device__ __forceinline__ ushort_t f2b(float f) {
    union { float f; uint_t i; } v; v.f = f;
    uint_t r = v.i + 0x7FFFu + ((v.i >> 16) & 1u);   // RNE
    return (ushort_t)(r >> 16);
}

// async global->LDS 16B per lane (HW: wave-uniform LDS base + lane*16)
typedef __attribute__((address_space(1))) const unsigned int gas_u32;
typedef __attribute__((address_space(3))) unsigned int las_u32;
__device__ __forceinline__ void gload16(const void* g, void* l) {
    __builtin_amdgcn_global_load_lds((gas_u32*)g, (las_u32*)l, 16, 0, 0);
}

// ---------------- fp32 -> bf16 conversion of the 3 MFMA weight mats ----------------
__global__ void cvtw3(const float* __restrict__ s0, ushort_t* __restrict__ d0,
                      const float* __restrict__ s1, ushort_t* __restrict__ d1,
                      const float* __restrict__ s2, ushort_t* __restrict__ d2) {
    int i = blockIdx.x * 256 + threadIdx.x;
    const int n0 = 1024 * 256, n1 = 144 * 512, n2 = 256 * 512;
    if (i < n0) d0[i] = f2b(s0[i]);
    else if (i < n0 + n1) d1[i - n0] = f2b(s1[i - n0]);
    else if (i < n0 + n1 + n2) d2[i - n0 - n1] = f2b(s2[i - n0 - n1]);
}

// ---------------- LN1 + build xm (both orders), fp32 in, bf16 out ----------------
__global__ void ln1_build_xm(const float* __restrict__ x,
                             const float* __restrict__ w,
                             const float* __restrict__ bb,
                             ushort_t* __restrict__ xm) {
    int row = blockIdx.x;            // b*4096 + l  (b in 0..3)
    int c = threadIdx.x;             // 0..255
    float v = x[(size_t)row * DIMC + c];
    float s1 = v, s2 = v * v;
    for (int off = 32; off; off >>= 1) {
        s1 += __shfl_xor(s1, off, 64);
        s2 += __shfl_xor(s2, off, 64);
    }
    __shared__ float sa[4], sb[4];
    int widx = c >> 6, lane = c & 63;
    if (lane == 0) { sa[widx] = s1; sb[widx] = s2; }
    __syncthreads();
    s1 = sa[0] + sa[1] + sa[2] + sa[3];
    s2 = sb[0] + sb[1] + sb[2] + sb[3];
    float mu = s1 * (1.0f / 256.0f);
    float var = s2 * (1.0f / 256.0f) - mu * mu;
    float xn = (v - mu) * rsqrtf(var + 1e-6f) * w[c] + bb[c];
    ushort_t o = f2b(xn);
    int b = row >> 12, l = row & 4095, i = l >> 6, j = l & 63;
    xm[((size_t)b * LSEQ + l) * DIMC + c] = o;
    xm[((size_t)(4 + b) * LSEQ + (j * 64 + i)) * DIMC + c] = o;
}

// ---------------- 128x128 LDS-tiled NT GEMM with global_load_lds staging ----------------
__global__ void __launch_bounds__(256, 4)
gemm128(const ushort_t* __restrict__ A,
        const ushort_t* __restrict__ W,
        ushort_t* __restrict__ C, int M, int N, int K) {
    __shared__ ushort_t Ash[128 * 32];
    __shared__ ushort_t Bsh[128 * 32];
    int tid = threadIdx.x;
    int lane = tid & 63, widx = tid >> 6;
    int wm = widx & 1, wn = widx >> 1;
    int l16 = lane & 15, quad = lane >> 4;
    int mblk = blockIdx.x * 128, nblk = blockIdx.y * 128;
    f32x4 acc[4][4];
    #pragma unroll
    for (int i = 0; i < 4; ++i)
        #pragma unroll
        for (int j = 0; j < 4; ++j)
            acc[i][j] = f32x4{0.0f, 0.0f, 0.0f, 0.0f};
    int srow = tid >> 2;
    int sseg = (tid & 3) * 8;
    bool jv[4];
    #pragma unroll
    for (int j = 0; j < 4; ++j) jv[j] = (nblk + wn * 64 + j * 16) < N;

    for (int k0 = 0; k0 < K; k0 += 32) {
        __syncthreads();
        #pragma unroll
        for (int q = 0; q < 2; ++q) {
            int row = q * 64 + srow;
            gload16(&A[(size_t)(mblk + row) * K + k0 + sseg], &Ash[row * 32 + sseg]);
            gload16(&W[(size_t)(nblk + row) * K + k0 + sseg], &Bsh[row * 32 + sseg]);
        }
        __syncthreads();
        short8 af[4], bf[4];
        #pragma unroll
        for (int i = 0; i < 4; ++i)
            af[i] = *(const short8*)&Ash[(wm * 64 + i * 16 + l16) * 32 + quad * 8];
        #pragma unroll
        for (int j = 0; j < 4; ++j)
            bf[j] = *(const short8*)&Bsh[(wn * 64 + j * 16 + l16) * 32 + quad * 8];
        #pragma unroll
        for (int i = 0; i < 4; ++i)
            #pragma unroll
            for (int j = 0; j < 4; ++j)
                if (jv[j])
                    acc[i][j] = __builtin_amdgcn_mfma_f32_16x16x32_bf16(af[i], bf[j], acc[i][j], 0, 0, 0);
    }
    #pragma unroll
    for (int i = 0; i < 4; ++i) {
        #pragma unroll
        for (int j = 0; j < 4; ++j) {
            if (!jv[j]) continue;
            int col = nblk + wn * 64 + j * 16 + l16;
            #pragma unroll
            for (int r = 0; r < 4; ++r) {
                int row = mblk + wm * 64 + i * 16 + quad * 4 + r;
                C[(size_t)row * N + col] = f2b(acc[i][j][r]);
            }
        }
    }
}

// ---------------- gemm128 variant: K=256, N=1024, split outputs at col 512 ----------------
__global__ void __launch_bounds__(256, 4)
gemm128_split(const ushort_t* __restrict__ A,
              const ushort_t* __restrict__ W,
              ushort_t* __restrict__ outX,   // cols 0..511
              ushort_t* __restrict__ outZ) { // cols 512..1023
    const int K = 256;
    __shared__ ushort_t Ash[128 * 32];
    __shared__ ushort_t Bsh[128 * 32];
    int tid = threadIdx.x;
    int lane = tid & 63, widx = tid >> 6;
    int wm = widx & 1, wn = widx >> 1;
    int l16 = lane & 15, quad = lane >> 4;
    int mblk = blockIdx.x * 128, nblk = blockIdx.y * 128;
    f32x4 acc[4][4];
    #pragma unroll
    for (int i = 0; i < 4; ++i)
        #pragma unroll
        for (int j = 0; j < 4; ++j)
            acc[i][j] = f32x4{0.0f, 0.0f, 0.0f, 0.0f};
    int srow = tid >> 2;
    int sseg = (tid & 3) * 8;
    for (int k0 = 0; k0 < K; k0 += 32) {
        __syncthreads();
        #pragma unroll
        for (int q = 0; q < 2; ++q) {
            int row = q * 64 + srow;
            gload16(&A[(size_t)(mblk + row) * K + k0 + sseg], &Ash[row * 32 + sseg]);
            gload16(&W[(size_t)(nblk + row) * K + k0 + sseg], &Bsh[row * 32 + sseg]);
        }
        __syncthreads();
        short8 af[4], bf[4];
        #pragma unroll
        for (int i = 0; i < 4; ++i)
            af[i] = *(const short8*)&Ash[(wm * 64 + i * 16 + l16) * 32 + quad * 8];
        #pragma unroll
        for (int j = 0; j < 4; ++j)
            bf[j] = *(const short8*)&Bsh[(wn * 64 + j * 16 + l16) * 32 + quad * 8];
        #pragma unroll
        for (int i = 0; i < 4; ++i)
            #pragma unroll
            for (int j = 0; j < 4; ++j)
                acc[i][j] = __builtin_amdgcn_mfma_f32_16x16x32_bf16(af[i], bf[j], acc[i][j], 0, 0, 0);
    }
    #pragma unroll
    for (int i = 0; i < 4; ++i) {
        #pragma unroll
        for (int j = 0; j < 4; ++j) {
            int colg = nblk + wn * 64 + j * 16 + l16;    // tile never straddles 512
            ushort_t* dst = (colg < 512) ? outX : outZ;
            int col = colg & 511;
            #pragma unroll
            for (int r = 0; r < 4; ++r) {
                int row = mblk + wm * 64 + i * 16 + quad * 4 + r;
                dst[(size_t)row * 512 + col] = f2b(acc[i][j][r]);
            }
        }
    }
}

// ---------------- tiled conv(4)+SiLU: all-coalesced, dual output ----------------
__global__ void conv_silu_t(const ushort_t* __restrict__ xh,
                            const float* __restrict__ cw,
                            const float* __restrict__ cb,
                            ushort_t* __restrict__ xc,
                            ushort_t* __restrict__ u_T) {
    int bt0 = blockIdx.x * 64;
    int d0  = blockIdx.y * 64;
    int b   = bt0 >> 12;
    int t0  = bt0 & 4095;
    __shared__ ushort_t tin[67][66];
    __shared__ ushort_t tout[64][66];
    int tid = threadIdx.x, lane = tid & 63, widx = tid >> 6;
    for (int r = widx; r < 67; r += 4) {
        int tt = t0 - 3 + r;
        tin[r][lane] = (tt >= 0) ? xh[((size_t)bt0 - 3 + r) * 512 + d0 + lane] : (ushort_t)0;
    }
    __syncthreads();
    for (int dd = widx; dd < 64; dd += 4) {
        int d = d0 + dd;
        float acc = cb[d];
        #pragma unroll
        for (int k = 0; k < 4; ++k)
            acc += cw[d * 4 + k] * b2f(tin[lane + k][dd]);
        float s = acc / (1.0f + __expf(-acc));
        ushort_t o = f2b(s);
        u_T[((size_t)b * 512 + d) * 4096 + t0 + lane] = o;
        tout[lane][dd] = o;
    }
    __syncthreads();
    for (int r = widx; r < 64; r += 4)
        xc[((size_t)bt0 + r) * 512 + d0 + lane] = tout[r][lane];
}

// ---------------- tiled dt/w: dt_T = softplus(...), w_T = dt*u  ----------------
__global__ void dt_sp_t(const ushort_t* __restrict__ xdbl,
                        const float* __restrict__ wdt,
                        const float* __restrict__ bdt,
                        const ushort_t* __restrict__ u_T,
                        ushort_t* __restrict__ dt_T,
                        ushort_t* __restrict__ w_T) {
    int bt0 = blockIdx.x * 64;
    int d0  = blockIdx.y * 64;
    int b   = bt0 >> 12;
    int t0  = bt0 & 4095;
    __shared__ float din[64][17];
    int tid = threadIdx.x;
    for (int i = tid; i < 64 * 16; i += 256) {
        int r = i >> 4, k = i & 15;
        din[r][k] = b2f(xdbl[((size_t)bt0 + r) * 144 + k]);
    }
    __syncthreads();
    int lane = tid & 63, widx = tid >> 6;
    for (int dd = widx; dd < 64; dd += 4) {
        int d = d0 + dd;
        float acc = bdt[d];
        #pragma unroll
        for (int k = 0; k < 16; ++k)
            acc += din[lane][k] * wdt[d * 16 + k];
        float sp = (acc > 20.0f) ? acc : log1pf(__expf(acc));
        size_t idx = ((size_t)b * 512 + d) * 4096 + t0 + lane;
        dt_T[idx] = f2b(sp);
        float uvv = b2f(u_T[idx]);
        w_T[idx] = f2b(sp * uvv);
    }
}

// ---------------- B/C pre-unpack: BCf[row][s] = (fp32 B, fp32 C) ----------------
__global__ void bcf_prep(const ushort_t* __restrict__ xdbl,
                         float2* __restrict__ BCf) {
    size_t gid = (size_t)blockIdx.x * 256 + threadIdx.x;  // over MROWS*64
    size_t row = gid >> 6;
    int s = (int)(gid & 63);
    const ushort_t* rp = xdbl + row * 144;
    BCf[gid] = make_float2(b2f(rp[16 + s]), b2f(rp[80 + s]));
}

// ---------------- selective scan v10: scan8 core + async fp32 B/C staging ----------------
template<int LVL>
__device__ __forceinline__ float merge_lvl_t(float left, float right, int lane) {
    bool bit = (lane >> LVL) & 1;
    float send = bit ? left : right;
    float keep = bit ? right : left;
    float recv;
    if constexpr (LVL == 0)
        recv = __int_as_float(__builtin_amdgcn_update_dpp(
            0, __float_as_int(send), 0xB1, 0xF, 0xF, false));   // quad_perm xor1
    else if constexpr (LVL == 1)
        recv = __int_as_float(__builtin_amdgcn_update_dpp(
            0, __float_as_int(send), 0x4E, 0xF, 0xF, false));   // quad_perm xor2
    else
        recv = __shfl_xor(send, 1 << LVL, 64);
    return keep + recv;
}

__global__ void __launch_bounds__(256, 4)
scan10(const ushort_t* __restrict__ dt_T,
       ushort_t* uT_ysT,
       const ushort_t* __restrict__ w_T,
       const float2* __restrict__ BCf,
       const float* __restrict__ Alog,
       const float* __restrict__ Dp) {
    __shared__ float2 BCsh[64][64];   // [t][s] fp32 pair; ds_read_b64, 2-way alias
    int tid = threadIdx.x;
    int lane = tid & 63, widx = tid >> 6;
    int wid = blockIdx.x * 4 + widx;
    int b = wid >> 9, d = wid & 511;
    float a2 = -__expf(Alog[d * 64 + lane]) * 1.442695041f;   // log2(e) folded
    float Dd = Dp[d];
    float h = 0.0f;
    size_t rowT = ((size_t)b * 512 + d) * 4096;
    uint_t rowTu = __builtin_amdgcn_readfirstlane((uint_t)rowT);
    size_t base = (size_t)b * LSEQ;
    for (int t0 = 0; t0 < LSEQ; t0 += 64) {
        __syncthreads();
        // async contiguous 32 KB slab: BCf[(base+t0)*64 .. +4096) -> BCsh
        {
            const char* gsrc = (const char*)(BCf + (((size_t)(base + t0)) << 6));
            char* ldst = (char*)&BCsh[0][0];
            size_t woff = (size_t)widx * 8192;
            #pragma unroll
            for (int it = 0; it < 8; ++it) {
                size_t o = woff + (size_t)it * 1024 + (size_t)lane * 16;
                gload16(gsrc + o, ldst + o);
            }
        }
        const uint_t* dtw = (const uint_t*)(dt_T + rowTu) + (t0 >> 1);
        const uint_t* wwp = (const uint_t*)(w_T + rowTu) + (t0 >> 1);
        float uv = b2f(uT_ysT[rowT + t0 + lane]);
        __syncthreads();
        float acc[4], s4, s5, yfin = 0.0f, v16 = 0.0f;
        #pragma unroll 1
        for (int j1 = 0; j1 < 4; ++j1) {
            #pragma unroll
            for (int jj = 0; jj < 16; ++jj) {
                int j = j1 * 16 + jj;
                uint_t pd = dtw[j >> 1];
                uint_t pw = wwp[j >> 1];
                float sdt = __uint_as_float((jj & 1) ? (pd & 0xFFFF0000u) : (pd << 16));
                float sw  = __uint_as_float((jj & 1) ? (pw & 0xFFFF0000u) : (pw << 16));
                float2 bc = BCsh[j][lane];          // single ds_read_b64
                float dA = __builtin_amdgcn_exp2f(sdt * a2);  // raw v_exp_f32
                float Bw = sw * bc.x;
                h = dA * h + Bw;
                float v = h * bc.y;
                const int dest = (jj == 15) ? 4 : __builtin_ctz(~(unsigned)jj);
                if (0 < dest) v = merge_lvl_t<0>(acc[0], v, lane);
                if (1 < dest) v = merge_lvl_t<1>(acc[1], v, lane);
                if (2 < dest) v = merge_lvl_t<2>(acc[2], v, lane);
                if (3 < dest) v = merge_lvl_t<3>(acc[3], v, lane);
                if (jj == 15) v16 = v;
                else acc[dest] = v;
            }
            if ((j1 & 1) == 0) {
                s4 = v16;
            } else {
                float m = merge_lvl_t<4>(s4, v16, lane);
                if (j1 == 1) s5 = m;
                else yfin = merge_lvl_t<5>(s5, m, lane);
            }
        }
        float y = yfin + uv * Dd;
        uT_ysT[rowT + t0 + lane] = f2b(y);
    }
}

// ---------------- gate + transpose: ys[bt,d] = ysT[b,d,t] * silu(z[bt,d]) ----------------
__global__ void gate_t(const ushort_t* __restrict__ ysT,
                       const ushort_t* __restrict__ zb,
                       ushort_t* __restrict__ ys) {
    int bt0 = blockIdx.x * 64;
    int d0  = blockIdx.y * 64;
    int b   = bt0 >> 12;
    int t0  = bt0 & 4095;
    __shared__ ushort_t tile[64][66];
    int tid = threadIdx.x, lane = tid & 63, widx = tid >> 6;
    for (int dd = widx; dd < 64; dd += 4)
        tile[dd][lane] = ysT[((size_t)b * 512 + d0 + dd) * 4096 + t0 + lane];
    __syncthreads();
    for (int r = widx; r < 64; r += 4) {
        float zv = b2f(zb[((size_t)bt0 + r) * 512 + d0 + lane]);
        float yv = b2f(tile[lane][r]);
        float g = zv / (1.0f + __expf(-zv));
        ys[((size_t)bt0 + r) * 512 + d0 + lane] = f2b(yv * g);
    }
}

// ---------------- final LN + transpose-combine + residual (fp32 out) ----------------
__global__ void final_ln_add(const ushort_t* __restrict__ outm,
                             const float* __restrict__ x,
                             const float* __restrict__ w,
                             const float* __restrict__ bb,
                             float* __restrict__ out) {
    int row = blockIdx.x;
    int c = threadIdx.x;
    int b = row >> 12, l = row & 4095, i = l >> 6, j = l & 63;
    size_t rA = ((size_t)b * LSEQ + l) * DIMC;
    size_t rB = ((size_t)(4 + b) * LSEQ + (j * 64 + i)) * DIMC;
    float va = b2f(outm[rA + c]);
    float vb = b2f(outm[rB + c]);
    float s1 = va, s2 = va * va, s3 = vb, s4 = vb * vb;
    for (int off = 32; off; off >>= 1) {
        s1 += __shfl_xor(s1, off, 64);
        s2 += __shfl_xor(s2, off, 64);
        s3 += __shfl_xor(s3, off, 64);
        s4 += __shfl_xor(s4, off, 64);
    }
    __shared__ float sm[4][4];
    int widx = c >> 6, lane = c & 63;
    if (lane == 0) { sm[widx][0] = s1; sm[widx][1] = s2; sm[widx][2] = s3; sm[widx][3] = s4; }
    __syncthreads();
    s1 = sm[0][0] + sm[1][0] + sm[2][0] + sm[3][0];
    s2 = sm[0][1] + sm[1][1] + sm[2][1] + sm[3][1];
    s3 = sm[0][2] + sm[1][2] + sm[2][2] + sm[3][2];
    s4 = sm[0][3] + sm[1][3] + sm[2][3] + sm[3][3];
    float muA = s1 * (1.0f / 256.0f), varA = s2 * (1.0f / 256.0f) - muA * muA;
    float muB = s3 * (1.0f / 256.0f), varB = s4 * (1.0f / 256.0f) - muB * muB;
    float lw = w[c], lb = bb[c];
    float ya = (va - muA) * rsqrtf(varA + 1e-6f) * lw + lb;
    float yb = (vb - muB) * rsqrtf(varB + 1e-6f) * lw + lb;
    float xo = x[(size_t)row * DIMC + c];
    out[(size_t)row * DIMC + c] = xo + ya + yb;
}

extern "C" void kernel_launch(void* const* d_in, const int* in_sizes, int n_in,
                              void* d_out, int out_size, void* d_ws, size_t ws_size,
                              hipStream_t stream) {
    const float* x      = (const float*)d_in[0];
    const float* ln1_w  = (const float*)d_in[1];
    const float* ln1_b  = (const float*)d_in[2];
    const float* ln2_w  = (const float*)d_in[3];
    const float* ln2_b  = (const float*)d_in[4];
    const float* W_in   = (const float*)d_in[5];
    const float* conv_w = (const float*)d_in[6];
    const float* conv_b = (const float*)d_in[7];
    const float* W_x    = (const float*)d_in[8];
    const float* W_dt   = (const float*)d_in[9];
    const float* b_dt   = (const float*)d_in[10];
    const float* A_log  = (const float*)d_in[11];
    const float* D_par  = (const float*)d_in[12];
    const float* W_out  = (const float*)d_in[13];
    float* out = (float*)d_out;

    // ---- workspace (~169 MB) ----
    char* ws = (char*)d_ws;
    size_t off = 0;
    ushort_t* wb_in  = (ushort_t*)(ws + off); off += (size_t)1024 * 256 * 2;
    ushort_t* wb_x   = (ushort_t*)(ws + off); off += (size_t)144 * 512 * 2;
    ushort_t* wb_out = (ushort_t*)(ws + off); off += (size_t)256 * 512 * 2;
    const size_t R0 = (size_t)MROWS * DIMC * 2;
    const size_t R1 = (size_t)MROWS * 512 * 2;
    ushort_t* r0 = (ushort_t*)(ws + off); off += R0;   // xm -> xdbl -> outm
    ushort_t* r1 = (ushort_t*)(ws + off); off += R1;   // xhalf -> dt_T
    ushort_t* r2 = (ushort_t*)(ws + off); off += R1;   // z
    ushort_t* r3 = (ushort_t*)(ws + off); off += R1;   // xc -> w_T -> ys
    ushort_t* r4 = (ushort_t*)(ws + off); off += R1;   // u_T -> ysT (in place)
    float2*   BCf = (float2*)(ws + off);  off += (size_t)MROWS * 64 * 8;  // 16.8 MB

    ushort_t* xm    = r0;
    ushort_t* xdbl  = r0;
    ushort_t* outm  = r0;
    ushort_t* xhalf = r1;
    ushort_t* dt_T  = r1;
    ushort_t* zb    = r2;
    ushort_t* xc    = r3;
    ushort_t* w_T   = r3;
    ushort_t* ys    = r3;
    ushort_t* u_T   = r4;

    // 0. convert MFMA weights fp32 -> bf16 (one launch)
    const int ncvt = 1024 * 256 + 144 * 512 + 256 * 512;
    hipLaunchKernelGGL(cvtw3, dim3((ncvt + 255) / 256), dim3(256), 0, stream,
                       W_in, wb_in, W_x, wb_x, W_out, wb_out);

    // A. LayerNorm + dual-order xm
    hipLaunchKernelGGL(ln1_build_xm, dim3(4 * LSEQ), dim3(256), 0, stream,
                       x, ln1_w, ln1_b, xm);
    // B. one launch: cols<512 -> xhalf, cols>=512 -> zb
    hipLaunchKernelGGL(gemm128_split, dim3(MROWS / 128, 8), dim3(256), 0, stream,
                       xm, wb_in, xhalf, zb);
    // C. tiled conv + SiLU: xhalf -> xc[bt,d] + u_T[b,d,t]
    hipLaunchKernelGGL(conv_silu_t, dim3(MROWS / 64, 8), dim3(256), 0, stream,
                       xhalf, conv_w, conv_b, xc, u_T);
    // D. x_dbl = xc @ W_x^T   (N=144, K=512)
    hipLaunchKernelGGL(gemm128, dim3(MROWS / 128, 2), dim3(256), 0, stream,
                       xc, wb_x, xdbl, MROWS, 144, 512);
    // E. dt_T = softplus(...), w_T = dt*u  [b,d,t]
    hipLaunchKernelGGL(dt_sp_t, dim3(MROWS / 64, 8), dim3(256), 0, stream,
                       xdbl, W_dt, b_dt, u_T, dt_T, w_T);
    // E2. unpack B/C to interleaved fp32
    hipLaunchKernelGGL(bcf_prep, dim3((size_t)MROWS * 64 / 256), dim3(256), 0, stream,
                       xdbl, BCf);
    // F. selective scan v10: u_T -> ysT in place
    hipLaunchKernelGGL(scan10, dim3(BS2 * 512 / 4), dim3(256), 0, stream,
                       dt_T, u_T, w_T, BCf, A_log, D_par);
    // G. gate + transpose: ys[bt,d] = ysT * silu(z)
    hipLaunchKernelGGL(gate_t, dim3(MROWS / 64, 8), dim3(256), 0, stream,
                       u_T, zb, ys);
    // H. outm = ys @ W_out^T   (N=256, K=512)
    hipLaunchKernelGGL(gemm128, dim3(MROWS / 128, 2), dim3(256), 0, stream,
                       ys, wb_out, outm, MROWS, 256, 512);
    // I. final LN + transpose combine + residual (fp32 out)
    hipLaunchKernelGGL(final_ln_add, dim3(4 * LSEQ), dim3(256), 0, stream,
                       outm, x, ln2_w, ln2_b, out);
}

// Round 16
// 727.152 us; speedup vs baseline: 1.5086x; 1.0159x over previous
//
#include <hip/hip_runtime.h>
#include <hip/hip_bf16.h>

typedef unsigned short ushort_t;
typedef unsigned int uint_t;
typedef __attribute__((ext_vector_type(8))) short short8;
typedef __attribute__((ext_vector_type(4))) float f32x4;

#define DIMC 256
#define D_INNER 512
#define D_STATE 64
#define DT_RANK 16
#define LSEQ 4096
#define BS2 8            // 2*BS batches through mamba
#define MROWS (BS2*LSEQ) // 32768

__device__ __forceinline__ float b2f(ushort_t u) {
    union { uint_t i; float f; } v; v.i = ((uint_t)u) << 16; return v.f;
}
__device__ __forceinline__ ushort_t f2b(float f) {
    union { float f; uint_t i; } v; v.f = f;
    uint_t r = v.i + 0x7FFFu + ((v.i >> 16) & 1u);   // RNE
    return (ushort_t)(r >> 16);
}

// async global->LDS 16B per lane (HW: wave-uniform LDS base + lane*16)
typedef __attribute__((address_space(1))) const unsigned int gas_u32;
typedef __attribute__((address_space(3))) unsigned int las_u32;
__device__ __forceinline__ void gload16(const void* g, void* l) {
    __builtin_amdgcn_global_load_lds((gas_u32*)g, (las_u32*)l, 16, 0, 0);
}

// ---------------- fp32 -> bf16 conversion of the 3 MFMA weight mats ----------------
__global__ void cvtw3(const float* __restrict__ s0, ushort_t* __restrict__ d0,
                      const float* __restrict__ s1, ushort_t* __restrict__ d1,
                      const float* __restrict__ s2, ushort_t* __restrict__ d2) {
    int i = blockIdx.x * 256 + threadIdx.x;
    const int n0 = 1024 * 256, n1 = 144 * 512, n2 = 256 * 512;
    if (i < n0) d0[i] = f2b(s0[i]);
    else if (i < n0 + n1) d1[i - n0] = f2b(s1[i - n0]);
    else if (i < n0 + n1 + n2) d2[i - n0 - n1] = f2b(s2[i - n0 - n1]);
}

// ---------------- LN1 + build xm (both orders), fp32 in, bf16 out ----------------
__global__ void ln1_build_xm(const float* __restrict__ x,
                             const float* __restrict__ w,
                             const float* __restrict__ bb,
                             ushort_t* __restrict__ xm) {
    int row = blockIdx.x;            // b*4096 + l  (b in 0..3)
    int c = threadIdx.x;             // 0..255
    float v = x[(size_t)row * DIMC + c];
    float s1 = v, s2 = v * v;
    for (int off = 32; off; off >>= 1) {
        s1 += __shfl_xor(s1, off, 64);
        s2 += __shfl_xor(s2, off, 64);
    }
    __shared__ float sa[4], sb[4];
    int widx = c >> 6, lane = c & 63;
    if (lane == 0) { sa[widx] = s1; sb[widx] = s2; }
    __syncthreads();
    s1 = sa[0] + sa[1] + sa[2] + sa[3];
    s2 = sb[0] + sb[1] + sb[2] + sb[3];
    float mu = s1 * (1.0f / 256.0f);
    float var = s2 * (1.0f / 256.0f) - mu * mu;
    float xn = (v - mu) * rsqrtf(var + 1e-6f) * w[c] + bb[c];
    ushort_t o = f2b(xn);
    int b = row >> 12, l = row & 4095, i = l >> 6, j = l & 63;
    xm[((size_t)b * LSEQ + l) * DIMC + c] = o;
    xm[((size_t)(4 + b) * LSEQ + (j * 64 + i)) * DIMC + c] = o;
}

// ---------------- 128x128 LDS-tiled NT GEMM with global_load_lds staging ----------------
__global__ void __launch_bounds__(256, 4)
gemm128(const ushort_t* __restrict__ A,
        const ushort_t* __restrict__ W,
        ushort_t* __restrict__ C, int M, int N, int K) {
    __shared__ ushort_t Ash[128 * 32];
    __shared__ ushort_t Bsh[128 * 32];
    int tid = threadIdx.x;
    int lane = tid & 63, widx = tid >> 6;
    int wm = widx & 1, wn = widx >> 1;
    int l16 = lane & 15, quad = lane >> 4;
    int mblk = blockIdx.x * 128, nblk = blockIdx.y * 128;
    f32x4 acc[4][4];
    #pragma unroll
    for (int i = 0; i < 4; ++i)
        #pragma unroll
        for (int j = 0; j < 4; ++j)
            acc[i][j] = f32x4{0.0f, 0.0f, 0.0f, 0.0f};
    int srow = tid >> 2;
    int sseg = (tid & 3) * 8;
    bool jv[4];
    #pragma unroll
    for (int j = 0; j < 4; ++j) jv[j] = (nblk + wn * 64 + j * 16) < N;

    for (int k0 = 0; k0 < K; k0 += 32) {
        __syncthreads();
        #pragma unroll
        for (int q = 0; q < 2; ++q) {
            int row = q * 64 + srow;
            gload16(&A[(size_t)(mblk + row) * K + k0 + sseg], &Ash[row * 32 + sseg]);
            gload16(&W[(size_t)(nblk + row) * K + k0 + sseg], &Bsh[row * 32 + sseg]);
        }
        __syncthreads();
        short8 af[4], bf[4];
        #pragma unroll
        for (int i = 0; i < 4; ++i)
            af[i] = *(const short8*)&Ash[(wm * 64 + i * 16 + l16) * 32 + quad * 8];
        #pragma unroll
        for (int j = 0; j < 4; ++j)
            bf[j] = *(const short8*)&Bsh[(wn * 64 + j * 16 + l16) * 32 + quad * 8];
        #pragma unroll
        for (int i = 0; i < 4; ++i)
            #pragma unroll
            for (int j = 0; j < 4; ++j)
                if (jv[j])
                    acc[i][j] = __builtin_amdgcn_mfma_f32_16x16x32_bf16(af[i], bf[j], acc[i][j], 0, 0, 0);
    }
    #pragma unroll
    for (int i = 0; i < 4; ++i) {
        #pragma unroll
        for (int j = 0; j < 4; ++j) {
            if (!jv[j]) continue;
            int col = nblk + wn * 64 + j * 16 + l16;
            #pragma unroll
            for (int r = 0; r < 4; ++r) {
                int row = mblk + wm * 64 + i * 16 + quad * 4 + r;
                C[(size_t)row * N + col] = f2b(acc[i][j][r]);
            }
        }
    }
}

// ---------------- gemm128 variant: K=256, N=1024, split outputs at col 512 ----------------
__global__ void __launch_bounds__(256, 4)
gemm128_split(const ushort_t* __restrict__ A,
              const ushort_t* __restrict__ W,
              ushort_t* __restrict__ outX,   // cols 0..511
              ushort_t* __restrict__ outZ) { // cols 512..1023
    const int K = 256;
    __shared__ ushort_t Ash[128 * 32];
    __shared__ ushort_t Bsh[128 * 32];
    int tid = threadIdx.x;
    int lane = tid & 63, widx = tid >> 6;
    int wm = widx & 1, wn = widx >> 1;
    int l16 = lane & 15, quad = lane >> 4;
    int mblk = blockIdx.x * 128, nblk = blockIdx.y * 128;
    f32x4 acc[4][4];
    #pragma unroll
    for (int i = 0; i < 4; ++i)
        #pragma unroll
        for (int j = 0; j < 4; ++j)
            acc[i][j] = f32x4{0.0f, 0.0f, 0.0f, 0.0f};
    int srow = tid >> 2;
    int sseg = (tid & 3) * 8;
    for (int k0 = 0; k0 < K; k0 += 32) {
        __syncthreads();
        #pragma unroll
        for (int q = 0; q < 2; ++q) {
            int row = q * 64 + srow;
            gload16(&A[(size_t)(mblk + row) * K + k0 + sseg], &Ash[row * 32 + sseg]);
            gload16(&W[(size_t)(nblk + row) * K + k0 + sseg], &Bsh[row * 32 + sseg]);
        }
        __syncthreads();
        short8 af[4], bf[4];
        #pragma unroll
        for (int i = 0; i < 4; ++i)
            af[i] = *(const short8*)&Ash[(wm * 64 + i * 16 + l16) * 32 + quad * 8];
        #pragma unroll
        for (int j = 0; j < 4; ++j)
            bf[j] = *(const short8*)&Bsh[(wn * 64 + j * 16 + l16) * 32 + quad * 8];
        #pragma unroll
        for (int i = 0; i < 4; ++i)
            #pragma unroll
            for (int j = 0; j < 4; ++j)
                acc[i][j] = __builtin_amdgcn_mfma_f32_16x16x32_bf16(af[i], bf[j], acc[i][j], 0, 0, 0);
    }
    #pragma unroll
    for (int i = 0; i < 4; ++i) {
        #pragma unroll
        for (int j = 0; j < 4; ++j) {
            int colg = nblk + wn * 64 + j * 16 + l16;    // tile never straddles 512
            ushort_t* dst = (colg < 512) ? outX : outZ;
            int col = colg & 511;
            #pragma unroll
            for (int r = 0; r < 4; ++r) {
                int row = mblk + wm * 64 + i * 16 + quad * 4 + r;
                dst[(size_t)row * 512 + col] = f2b(acc[i][j][r]);
            }
        }
    }
}

// ---------------- tiled conv(4)+SiLU: all-coalesced, dual output ----------------
__global__ void conv_silu_t(const ushort_t* __restrict__ xh,
                            const float* __restrict__ cw,
                            const float* __restrict__ cb,
                            ushort_t* __restrict__ xc,
                            ushort_t* __restrict__ u_T) {
    int bt0 = blockIdx.x * 64;
    int d0  = blockIdx.y * 64;
    int b   = bt0 >> 12;
    int t0  = bt0 & 4095;
    __shared__ ushort_t tin[67][66];
    __shared__ ushort_t tout[64][66];
    int tid = threadIdx.x, lane = tid & 63, widx = tid >> 6;
    for (int r = widx; r < 67; r += 4) {
        int tt = t0 - 3 + r;
        tin[r][lane] = (tt >= 0) ? xh[((size_t)bt0 - 3 + r) * 512 + d0 + lane] : (ushort_t)0;
    }
    __syncthreads();
    for (int dd = widx; dd < 64; dd += 4) {
        int d = d0 + dd;
        float acc = cb[d];
        #pragma unroll
        for (int k = 0; k < 4; ++k)
            acc += cw[d * 4 + k] * b2f(tin[lane + k][dd]);
        float s = acc / (1.0f + __expf(-acc));
        ushort_t o = f2b(s);
        u_T[((size_t)b * 512 + d) * 4096 + t0 + lane] = o;
        tout[lane][dd] = o;
    }
    __syncthreads();
    for (int r = widx; r < 64; r += 4)
        xc[((size_t)bt0 + r) * 512 + d0 + lane] = tout[r][lane];
}

// ---------------- tiled dt/w (+fused B/C unpack on y==0 blocks) ----------------
__global__ void dt_sp_t(const ushort_t* __restrict__ xdbl,
                        const float* __restrict__ wdt,
                        const float* __restrict__ bdt,
                        const ushort_t* __restrict__ u_T,
                        ushort_t* __restrict__ dt_T,
                        ushort_t* __restrict__ w_T,
                        float2* __restrict__ BCf) {
    int bt0 = blockIdx.x * 64;
    int d0  = blockIdx.y * 64;
    int b   = bt0 >> 12;
    int t0  = bt0 & 4095;
    __shared__ float din[64][17];
    int tid = threadIdx.x;
    for (int i = tid; i < 64 * 16; i += 256) {
        int r = i >> 4, k = i & 15;
        din[r][k] = b2f(xdbl[((size_t)bt0 + r) * 144 + k]);
    }
    __syncthreads();
    int lane = tid & 63, widx = tid >> 6;
    for (int dd = widx; dd < 64; dd += 4) {
        int d = d0 + dd;
        float acc = bdt[d];
        #pragma unroll
        for (int k = 0; k < 16; ++k)
            acc += din[lane][k] * wdt[d * 16 + k];
        float sp = (acc > 20.0f) ? acc : log1pf(__expf(acc));
        size_t idx = ((size_t)b * 512 + d) * 4096 + t0 + lane;
        dt_T[idx] = f2b(sp);
        float uvv = b2f(u_T[idx]);
        w_T[idx] = f2b(sp * uvv);
    }
    // fused B/C unpack (one d-slice of blocks covers it; d-independent data)
    if (blockIdx.y == 0) {
        for (int i = tid; i < 64 * 64; i += 256) {
            size_t row = (size_t)bt0 + (i >> 6);
            int s = i & 63;
            const ushort_t* rp = xdbl + row * 144;
            BCf[(row << 6) + s] = make_float2(b2f(rp[16 + s]), b2f(rp[80 + s]));
        }
    }
}

// ---------------- selective scan v10: scan8 core + async fp32 B/C staging ----------------
template<int LVL>
__device__ __forceinline__ float merge_lvl_t(float left, float right, int lane) {
    bool bit = (lane >> LVL) & 1;
    float send = bit ? left : right;
    float keep = bit ? right : left;
    float recv;
    if constexpr (LVL == 0)
        recv = __int_as_float(__builtin_amdgcn_update_dpp(
            0, __float_as_int(send), 0xB1, 0xF, 0xF, false));   // quad_perm xor1
    else if constexpr (LVL == 1)
        recv = __int_as_float(__builtin_amdgcn_update_dpp(
            0, __float_as_int(send), 0x4E, 0xF, 0xF, false));   // quad_perm xor2
    else
        recv = __shfl_xor(send, 1 << LVL, 64);
    return keep + recv;
}

__global__ void __launch_bounds__(256, 4)
scan10(const ushort_t* __restrict__ dt_T,
       ushort_t* uT_ysT,
       const ushort_t* __restrict__ w_T,
       const float2* __restrict__ BCf,
       const float* __restrict__ Alog,
       const float* __restrict__ Dp) {
    __shared__ float2 BCsh[64][64];   // [t][s] fp32 pair; ds_read_b64, 2-way alias
    int tid = threadIdx.x;
    int lane = tid & 63, widx = tid >> 6;
    int wid = blockIdx.x * 4 + widx;
    int b = wid >> 9, d = wid & 511;
    float a2 = -__expf(Alog[d * 64 + lane]) * 1.442695041f;   // log2(e) folded
    float Dd = Dp[d];
    float h = 0.0f;
    size_t rowT = ((size_t)b * 512 + d) * 4096;
    uint_t rowTu = __builtin_amdgcn_readfirstlane((uint_t)rowT);
    size_t base = (size_t)b * LSEQ;
    for (int t0 = 0; t0 < LSEQ; t0 += 64) {
        __syncthreads();
        // async contiguous 32 KB slab: BCf[(base+t0)*64 .. +4096) -> BCsh
        {
            const char* gsrc = (const char*)(BCf + (((size_t)(base + t0)) << 6));
            char* ldst = (char*)&BCsh[0][0];
            size_t woff = (size_t)widx * 8192;
            #pragma unroll
            for (int it = 0; it < 8; ++it) {
                size_t o = woff + (size_t)it * 1024 + (size_t)lane * 16;
                gload16(gsrc + o, ldst + o);
            }
        }
        const uint_t* dtw = (const uint_t*)(dt_T + rowTu) + (t0 >> 1);
        const uint_t* wwp = (const uint_t*)(w_T + rowTu) + (t0 >> 1);
        float uv = b2f(uT_ysT[rowT + t0 + lane]);
        __syncthreads();
        float acc[4], s4, s5, yfin = 0.0f, v16 = 0.0f;
        #pragma unroll 1
        for (int j1 = 0; j1 < 4; ++j1) {
            #pragma unroll
            for (int jj = 0; jj < 16; ++jj) {
                int j = j1 * 16 + jj;
                uint_t pd = dtw[j >> 1];
                uint_t pw = wwp[j >> 1];
                float sdt = __uint_as_float((jj & 1) ? (pd & 0xFFFF0000u) : (pd << 16));
                float sw  = __uint_as_float((jj & 1) ? (pw & 0xFFFF0000u) : (pw << 16));
                float2 bc = BCsh[j][lane];          // single ds_read_b64
                float dA = __builtin_amdgcn_exp2f(sdt * a2);  // raw v_exp_f32
                float Bw = sw * bc.x;
                h = dA * h + Bw;
                float v = h * bc.y;
                const int dest = (jj == 15) ? 4 : __builtin_ctz(~(unsigned)jj);
                if (0 < dest) v = merge_lvl_t<0>(acc[0], v, lane);
                if (1 < dest) v = merge_lvl_t<1>(acc[1], v, lane);
                if (2 < dest) v = merge_lvl_t<2>(acc[2], v, lane);
                if (3 < dest) v = merge_lvl_t<3>(acc[3], v, lane);
                if (jj == 15) v16 = v;
                else acc[dest] = v;
            }
            if ((j1 & 1) == 0) {
                s4 = v16;
            } else {
                float m = merge_lvl_t<4>(s4, v16, lane);
                if (j1 == 1) s5 = m;
                else yfin = merge_lvl_t<5>(s5, m, lane);
            }
        }
        float y = yfin + uv * Dd;
        uT_ysT[rowT + t0 + lane] = f2b(y);
    }
}

// ---------------- gate + transpose: ys[bt,d] = ysT[b,d,t] * silu(z[bt,d]) ----------------
__global__ void gate_t(const ushort_t* __restrict__ ysT,
                       const ushort_t* __restrict__ zb,
                       ushort_t* __restrict__ ys) {
    int bt0 = blockIdx.x * 64;
    int d0  = blockIdx.y * 64;
    int b   = bt0 >> 12;
    int t0  = bt0 & 4095;
    __shared__ ushort_t tile[64][66];
    int tid = threadIdx.x, lane = tid & 63, widx = tid >> 6;
    for (int dd = widx; dd < 64; dd += 4)
        tile[dd][lane] = ysT[((size_t)b * 512 + d0 + dd) * 4096 + t0 + lane];
    __syncthreads();
    for (int r = widx; r < 64; r += 4) {
        float zv = b2f(zb[((size_t)bt0 + r) * 512 + d0 + lane]);
        float yv = b2f(tile[lane][r]);
        float g = zv / (1.0f + __expf(-zv));
        ys[((size_t)bt0 + r) * 512 + d0 + lane] = f2b(yv * g);
    }
}

// ---------------- final LN + transpose-combine + residual (fp32 out) ----------------
__global__ void final_ln_add(const ushort_t* __restrict__ outm,
                             const float* __restrict__ x,
                             const float* __restrict__ w,
                             const float* __restrict__ bb,
                             float* __restrict__ out) {
    int row = blockIdx.x;
    int c = threadIdx.x;
    int b = row >> 12, l = row & 4095, i = l >> 6, j = l & 63;
    size_t rA = ((size_t)b * LSEQ + l) * DIMC;
    size_t rB = ((size_t)(4 + b) * LSEQ + (j * 64 + i)) * DIMC;
    float va = b2f(outm[rA + c]);
    float vb = b2f(outm[rB + c]);
    float s1 = va, s2 = va * va, s3 = vb, s4 = vb * vb;
    for (int off = 32; off; off >>= 1) {
        s1 += __shfl_xor(s1, off, 64);
        s2 += __shfl_xor(s2, off, 64);
        s3 += __shfl_xor(s3, off, 64);
        s4 += __shfl_xor(s4, off, 64);
    }
    __shared__ float sm[4][4];
    int widx = c >> 6, lane = c & 63;
    if (lane == 0) { sm[widx][0] = s1; sm[widx][1] = s2; sm[widx][2] = s3; sm[widx][3] = s4; }
    __syncthreads();
    s1 = sm[0][0] + sm[1][0] + sm[2][0] + sm[3][0];
    s2 = sm[0][1] + sm[1][1] + sm[2][1] + sm[3][1];
    s3 = sm[0][2] + sm[1][2] + sm[2][2] + sm[3][2];
    s4 = sm[0][3] + sm[1][3] + sm[2][3] + sm[3][3];
    float muA = s1 * (1.0f / 256.0f), varA = s2 * (1.0f / 256.0f) - muA * muA;
    float muB = s3 * (1.0f / 256.0f), varB = s4 * (1.0f / 256.0f) - muB * muB;
    float lw = w[c], lb = bb[c];
    float ya = (va - muA) * rsqrtf(varA + 1e-6f) * lw + lb;
    float yb = (vb - muB) * rsqrtf(varB + 1e-6f) * lw + lb;
    float xo = x[(size_t)row * DIMC + c];
    out[(size_t)row * DIMC + c] = xo + ya + yb;
}

extern "C" void kernel_launch(void* const* d_in, const int* in_sizes, int n_in,
                              void* d_out, int out_size, void* d_ws, size_t ws_size,
                              hipStream_t stream) {
    const float* x      = (const float*)d_in[0];
    const float* ln1_w  = (const float*)d_in[1];
    const float* ln1_b  = (const float*)d_in[2];
    const float* ln2_w  = (const float*)d_in[3];
    const float* ln2_b  = (const float*)d_in[4];
    const float* W_in   = (const float*)d_in[5];
    const float* conv_w = (const float*)d_in[6];
    const float* conv_b = (const float*)d_in[7];
    const float* W_x    = (const float*)d_in[8];
    const float* W_dt   = (const float*)d_in[9];
    const float* b_dt   = (const float*)d_in[10];
    const float* A_log  = (const float*)d_in[11];
    const float* D_par  = (const float*)d_in[12];
    const float* W_out  = (const float*)d_in[13];
    float* out = (float*)d_out;

    // ---- workspace (~169 MB) ----
    char* ws = (char*)d_ws;
    size_t off = 0;
    ushort_t* wb_in  = (ushort_t*)(ws + off); off += (size_t)1024 * 256 * 2;
    ushort_t* wb_x   = (ushort_t*)(ws + off); off += (size_t)144 * 512 * 2;
    ushort_t* wb_out = (ushort_t*)(ws + off); off += (size_t)256 * 512 * 2;
    const size_t R0 = (size_t)MROWS * DIMC * 2;
    const size_t R1 = (size_t)MROWS * 512 * 2;
    ushort_t* r0 = (ushort_t*)(ws + off); off += R0;   // xm -> xdbl -> outm
    ushort_t* r1 = (ushort_t*)(ws + off); off += R1;   // xhalf -> dt_T
    ushort_t* r2 = (ushort_t*)(ws + off); off += R1;   // z
    ushort_t* r3 = (ushort_t*)(ws + off); off += R1;   // xc -> w_T -> ys
    ushort_t* r4 = (ushort_t*)(ws + off); off += R1;   // u_T -> ysT (in place)
    float2*   BCf = (float2*)(ws + off);  off += (size_t)MROWS * 64 * 8;  // 16.8 MB

    ushort_t* xm    = r0;
    ushort_t* xdbl  = r0;
    ushort_t* outm  = r0;
    ushort_t* xhalf = r1;
    ushort_t* dt_T  = r1;
    ushort_t* zb    = r2;
    ushort_t* xc    = r3;
    ushort_t* w_T   = r3;
    ushort_t* ys    = r3;
    ushort_t* u_T   = r4;

    // 0. convert MFMA weights fp32 -> bf16 (one launch)
    const int ncvt = 1024 * 256 + 144 * 512 + 256 * 512;
    hipLaunchKernelGGL(cvtw3, dim3((ncvt + 255) / 256), dim3(256), 0, stream,
                       W_in, wb_in, W_x, wb_x, W_out, wb_out);

    // A. LayerNorm + dual-order xm
    hipLaunchKernelGGL(ln1_build_xm, dim3(4 * LSEQ), dim3(256), 0, stream,
                       x, ln1_w, ln1_b, xm);
    // B. one launch: cols<512 -> xhalf, cols>=512 -> zb
    hipLaunchKernelGGL(gemm128_split, dim3(MROWS / 128, 8), dim3(256), 0, stream,
                       xm, wb_in, xhalf, zb);
    // C. tiled conv + SiLU: xhalf -> xc[bt,d] + u_T[b,d,t]
    hipLaunchKernelGGL(conv_silu_t, dim3(MROWS / 64, 8), dim3(256), 0, stream,
                       xhalf, conv_w, conv_b, xc, u_T);
    // D. x_dbl = xc @ W_x^T   (N=144, K=512)
    hipLaunchKernelGGL(gemm128, dim3(MROWS / 128, 2), dim3(256), 0, stream,
                       xc, wb_x, xdbl, MROWS, 144, 512);
    // E. dt_T = softplus(...), w_T = dt*u, + fused B/C fp32 unpack
    hipLaunchKernelGGL(dt_sp_t, dim3(MROWS / 64, 8), dim3(256), 0, stream,
                       xdbl, W_dt, b_dt, u_T, dt_T, w_T, BCf);
    // F. selective scan v10: u_T -> ysT in place
    hipLaunchKernelGGL(scan10, dim3(BS2 * 512 / 4), dim3(256), 0, stream,
                       dt_T, u_T, w_T, BCf, A_log, D_par);
    // G. gate + transpose: ys[bt,d] = ysT * silu(z)
    hipLaunchKernelGGL(gate_t, dim3(MROWS / 64, 8), dim3(256), 0, stream,
                       u_T, zb, ys);
    // H. outm = ys @ W_out^T   (N=256, K=512)
    hipLaunchKernelGGL(gemm128, dim3(MROWS / 128, 2), dim3(256), 0, stream,
                       ys, wb_out, outm, MROWS, 256, 512);
    // I. final LN + transpose combine + residual (fp32 out)
    hipLaunchKernelGGL(final_ln_add, dim3(4 * LSEQ), dim3(256), 0, stream,
                       outm, x, ln2_w, ln2_b, out);
}